// Round 10
// baseline (282.086 us; speedup 1.0000x reference)
//
#include <hip/hip_runtime.h>
#include <hip/hip_bf16.h>

#define B_ 8
#define E_ 2048
#define N_ 2048
#define F_ 128

#define BM 64      // hyperedge rows per block (4 m-tiles of 16)
#define MT 4       // m-tiles
#define BK 64      // K chunk (elements)
#define MP 136     // msg LDS pitch

using bf16x8 = __bf16 __attribute__((ext_vector_type(8)));
using fx4    = float __attribute__((ext_vector_type(4)));

// Fully fused: node transpose (block-owned tile, flag handshake) + W convert +
// adj stream/bitpack + GEMM1 + norm + GEMM2 + bias/relu. One launch.
// flags[0..7] = per-batch tile ready bitmask; flags[8] = W-done counter.
__global__ __launch_bounds__(256, 1) void v2h_fused(const float* __restrict__ node,
                                                    const float* __restrict__ adj,
                                                    const float* __restrict__ W,
                                                    const float* __restrict__ bias,
                                                    __bf16* __restrict__ nodeT,
                                                    __bf16* __restrict__ Wb,
                                                    unsigned* __restrict__ flags,
                                                    float* __restrict__ out) {
    __shared__ __align__(16) __bf16 Bs[2][128][64];          // 32 KB, swizzled DMA layout
    __shared__ __align__(16) unsigned long long Abits[2][64];// 1 KB, dbuf bit tiles
    __shared__ __align__(16) float normS[BM];                // 256 B
    __shared__ __align__(16) __bf16 Ms[BM * MP];             // 17.4 KB

    const int t    = threadIdx.x;
    const int bid  = blockIdx.x;
    const int b    = bid & 7;            // batch; all blocks of b share an XCD (bid%8)
    const int j    = bid >> 3;           // 0..31: e-tile index AND owned n-tile index
    const int e0   = j * BM;
    const int w    = t >> 6;             // wave id = f-group (32 cols)
    const int lane = t & 63;
    const int l15  = lane & 15;
    const int quad = lane >> 4;

    // ---- Phase 1: transpose own node tile: n in [j*64, j*64+64) of batch b ----
    {
        const int f = t & 127;
#pragma unroll
        for (int u = 0; u < 2; ++u) {
            const int nb = j * 64 + u * 32 + (t >> 7) * 16;
            const float* src = node + ((size_t)b * N_ + nb) * F_ + f;
            __bf16 h[16];
#pragma unroll
            for (int i = 0; i < 16; ++i)
                h[i] = (__bf16)src[(size_t)i * F_];
            __bf16* dst = nodeT + ((size_t)b * F_ + f) * N_ + nb;
            *(uint4*)&dst[0] = *(const uint4*)&h[0];
            *(uint4*)&dst[8] = *(const uint4*)&h[8];
        }
    }
    __syncthreads();                     // all threads' global stores complete
    if (t == 0) {
        __threadfence();                 // release
        atomicOr(&flags[b], 1u << j);
    }

    // ---- W convert (blocks 0..15 only; needed first at epilogue) ----
    if (bid < 16) {
        int idx = bid * 256 + t;         // 0..4095
        float4 v = *(const float4*)&W[idx * 4];
        __bf16 o[4] = {(__bf16)v.x, (__bf16)v.y, (__bf16)v.z, (__bf16)v.w};
        *(uint2*)&Wb[idx * 4] = *(const uint2*)o;
        __syncthreads();
        if (t == 0) { __threadfence(); atomicAdd(&flags[8], 1u); }
    }

    // ---- adj stream assignment: row w*16+(lane>>2), col-seg (lane&3)*16 ----
    const int ar   = lane >> 2;          // 0..15
    const int acs  = lane & 3;           // 0..3
    const int arow = w * 16 + ar;        // 0..63
    const float* aRow = adj + ((size_t)b * E_ + e0 + arow) * N_ + acs * 16;
    const __bf16* nTB = nodeT + (size_t)b * F_ * N_;

    auto issue_dma = [&](int k0, int buf) {
#pragma unroll
        for (int p = 0; p < 4; ++p) {
            int idx = t + 256 * p;               // 0..1023
            int f   = idx >> 3;                  // 0..127
            int sl  = idx & 7;                   // LDS slot
            int g   = sl ^ (f & 7);              // global granule (XOR swizzle)
            const __bf16* src = nTB + (size_t)f * N_ + k0 + g * 8;
            __bf16* dst = &Bs[buf][0][0] + (size_t)(w * 64 + 256 * p) * 8; // wave-uniform
            __builtin_amdgcn_global_load_lds(
                (const __attribute__((address_space(1))) void*)src,
                (__attribute__((address_space(3))) void*)dst, 16, 0, 0);
        }
    };

    auto cvt16 = [](float4 v0, float4 v1, float4 v2, float4 v3) -> unsigned {
        unsigned m = 0;
        m |= (v0.x == -1.f) ? 1u     : 0u;
        m |= (v0.y == -1.f) ? 2u     : 0u;
        m |= (v0.z == -1.f) ? 4u     : 0u;
        m |= (v0.w == -1.f) ? 8u     : 0u;
        m |= (v1.x == -1.f) ? 16u    : 0u;
        m |= (v1.y == -1.f) ? 32u    : 0u;
        m |= (v1.z == -1.f) ? 64u    : 0u;
        m |= (v1.w == -1.f) ? 128u   : 0u;
        m |= (v2.x == -1.f) ? 256u   : 0u;
        m |= (v2.y == -1.f) ? 512u   : 0u;
        m |= (v2.z == -1.f) ? 1024u  : 0u;
        m |= (v2.w == -1.f) ? 2048u  : 0u;
        m |= (v3.x == -1.f) ? 4096u  : 0u;
        m |= (v3.y == -1.f) ? 8192u  : 0u;
        m |= (v3.z == -1.f) ? 16384u : 0u;
        m |= (v3.w == -1.f) ? 32768u : 0u;
        return m;
    };

    auto unpack = [](unsigned byte) -> bf16x8 {
        union { unsigned u[4]; bf16x8 v; } r;
        r.u[0] = ((byte &   1u) ? 0x3F80u : 0u) | ((byte &   2u) ? 0x3F800000u : 0u);
        r.u[1] = ((byte &   4u) ? 0x3F80u : 0u) | ((byte &   8u) ? 0x3F800000u : 0u);
        r.u[2] = ((byte &  16u) ? 0x3F80u : 0u) | ((byte &  32u) ? 0x3F800000u : 0u);
        r.u[3] = ((byte &  64u) ? 0x3F80u : 0u) | ((byte & 128u) ? 0x3F800000u : 0u);
        return r.v;
    };

    fx4 acc[MT][2] = {};
    int cnt = 0;
    unsigned seen = 1u << j;             // thread-0-only ready cache (own tile set)

    // ---- prologue on rotated tile order: tile(m) = (m + j) & 31 ----
    float4 a0 = *(const float4*)(aRow + j * BK + 0);
    float4 a1 = *(const float4*)(aRow + j * BK + 4);
    float4 a2 = *(const float4*)(aRow + j * BK + 8);
    float4 a3 = *(const float4*)(aRow + j * BK + 12);
    issue_dma(j * BK, 0);                // own tile: ready by construction
    {
        unsigned bits = cvt16(a0, a1, a2, a3);
        ((unsigned short*)&Abits[0][arow])[acs] = (unsigned short)bits;
        cnt += __popc(bits);
    }
    {
        const float* ap = aRow + (((j + 1) & 31) * BK);
        a0 = *(const float4*)(ap + 0);
        a1 = *(const float4*)(ap + 4);
        a2 = *(const float4*)(ap + 8);
        a3 = *(const float4*)(ap + 12);
    }

#pragma unroll
    for (int m = 0; m < 32; ++m) {
        const int buf = m & 1;
        const int ktn = (m + 1 + j) & 31;        // tile for next iter

        // ensure next tile transposed (thread 0; one mask read covers all tiles)
        if (m < 31 && t == 0 && !((seen >> ktn) & 1)) {
            unsigned msk;
            while (!(((msk = atomicOr(&flags[b], 0u)) >> ktn) & 1))
                __builtin_amdgcn_s_sleep(8);
            seen |= msk;
            __threadfence();                     // acquire
        }
        __syncthreads();   // drains B-DMA(m) + adj regs; Abits[buf] visible; poll done

        if (m < 31) {
            issue_dma(ktn * BK, buf ^ 1);
            unsigned bits = cvt16(a0, a1, a2, a3);   // tile m+1
            ((unsigned short*)&Abits[buf ^ 1][arow])[acs] = (unsigned short)bits;
            cnt += __popc(bits);
        }
        if (m < 30) {
            const float* ap = aRow + (((m + 2 + j) & 31) * BK);
            a0 = *(const float4*)(ap + 0);
            a1 = *(const float4*)(ap + 4);
            a2 = *(const float4*)(ap + 8);
            a3 = *(const float4*)(ap + 12);
        }

        // ---- A fragments from Abits[buf]: byte (ks*4+quad) of row-u64 ----
        bf16x8 af0[MT], af1[MT];
#pragma unroll
        for (int mt = 0; mt < MT; ++mt) {
            unsigned long long v = Abits[buf][mt * 16 + l15];
            unsigned lo = (unsigned)v, hi = (unsigned)(v >> 32);
            af0[mt] = unpack((lo >> (8 * quad)) & 255u);
            af1[mt] = unpack((hi >> (8 * quad)) & 255u);
        }

        // ---- B frag = row f, k-granule qg, at swizzled slot qg^(f&7); 4 m-tiles ----
#pragma unroll
        for (int ft = 0; ft < 2; ++ft) {
            int f  = w * 32 + ft * 16 + l15;
            int q0 = quad ^ (f & 7);
            int q1 = (4 + quad) ^ (f & 7);
            bf16x8 b0 = *(const bf16x8*)&Bs[buf][f][q0 * 8];
#pragma unroll
            for (int mt = 0; mt < MT; ++mt)
                acc[mt][ft] = __builtin_amdgcn_mfma_f32_16x16x32_bf16(af0[mt], b0, acc[mt][ft], 0, 0, 0);
            bf16x8 b1 = *(const bf16x8*)&Bs[buf][f][q1 * 8];
#pragma unroll
            for (int mt = 0; mt < MT; ++mt)
                acc[mt][ft] = __builtin_amdgcn_mfma_f32_16x16x32_bf16(af1[mt], b1, acc[mt][ft], 0, 0, 0);
        }
    }

    // ---- norm: reduce count over the 4 col-segment threads of each row ----
    {
        float c = (float)cnt;
        c += __shfl_xor(c, 1);
        c += __shfl_xor(c, 2);
        if (acs == 0)
            normS[arow] = 1.f / fmaxf(c, 1.f);
    }
    __syncthreads();

    // ---- scale by 1/count, write msg bf16 to LDS in [m][f] layout ----
    const int rbase = quad * 4;
    float4 rn[MT];
#pragma unroll
    for (int mt = 0; mt < MT; ++mt)
        rn[mt] = *(const float4*)&normS[mt * 16 + rbase];

#pragma unroll
    for (int ft = 0; ft < 2; ++ft) {
        int fcol = w * 32 + ft * 16 + l15;
#pragma unroll
        for (int mt = 0; mt < MT; ++mt) {
            const float* rr = (const float*)&rn[mt];
#pragma unroll
            for (int r = 0; r < 4; ++r)
                Ms[(mt * 16 + rbase + r) * MP + fcol] = (__bf16)(acc[mt][ft][r] * rr[r]);
        }
    }
    // ensure Wb fully converted (trivially true by now; one atomic read)
    if (t == 0) {
        while (atomicAdd(&flags[8], 0u) < 16u)
            __builtin_amdgcn_s_sleep(8);
        __threadfence();
    }
    __syncthreads();

    // ---- second GEMM: out[m][g] = sum_f msg[m][f] * W[g][f]; W direct from L2 ----
    fx4 acc2[MT][2] = {};
#pragma unroll
    for (int ks = 0; ks < 4; ++ks) {
        bf16x8 afm[MT];
#pragma unroll
        for (int mt = 0; mt < MT; ++mt)
            afm[mt] = *(const bf16x8*)&Ms[(mt * 16 + l15) * MP + ks * 32 + quad * 8];
#pragma unroll
        for (int gt = 0; gt < 2; ++gt) {
            int g = w * 32 + gt * 16 + l15;
            bf16x8 wfr = *(const bf16x8*)&Wb[(size_t)g * F_ + ks * 32 + quad * 8];
#pragma unroll
            for (int mt = 0; mt < MT; ++mt)
                acc2[mt][gt] = __builtin_amdgcn_mfma_f32_16x16x32_bf16(afm[mt], wfr, acc2[mt][gt], 0, 0, 0);
        }
    }

    // ---- bias + relu + store (all m-tiles) ----
#pragma unroll
    for (int gt = 0; gt < 2; ++gt) {
        int g = w * 32 + gt * 16 + l15;
        float bb = bias[g];
#pragma unroll
        for (int mt = 0; mt < MT; ++mt) {
#pragma unroll
            for (int r = 0; r < 4; ++r) {
                int e = e0 + mt * 16 + rbase + r;
                float v = acc2[mt][gt][r] + bb;
                out[((size_t)b * E_ + e) * F_ + g] = fmaxf(v, 0.f);
            }
        }
    }
}

extern "C" void kernel_launch(void* const* d_in, const int* in_sizes, int n_in,
                              void* d_out, int out_size, void* d_ws, size_t ws_size,
                              hipStream_t stream) {
    const float* node = (const float*)d_in[0];   // [B,N,F]
    const float* adj  = (const float*)d_in[1];   // [B,E,N]
    const float* W    = (const float*)d_in[2];   // [F,F]
    const float* bias = (const float*)d_in[3];   // [F]
    float* out = (float*)d_out;                  // [B,E,F]

    char* ws = (char*)d_ws;
    __bf16*   nodeT = (__bf16*)ws;                               // 8 MB
    __bf16*   Wb    = (__bf16*)(ws + 8 * 1024 * 1024);           // 32 KB
    unsigned* flags = (unsigned*)(ws + 8 * 1024 * 1024 + 65536); // 36 B used

    hipMemsetAsync(flags, 0, 64, stream);        // zero handshake flags each launch
    v2h_fused<<<256, 256, 0, stream>>>(node, adj, W, bias, nodeT, Wb, flags, out);
}

// Round 11
// 231.590 us; speedup vs baseline: 1.2180x; 1.2180x over previous
//
#include <hip/hip_runtime.h>
#include <hip/hip_bf16.h>

#define B_ 8
#define E_ 2048
#define N_ 2048
#define F_ 128

#define BM 64      // hyperedge rows per block (4 m-tiles of 16)
#define MT 4       // m-tiles
#define BK 64      // K chunk (elements)
#define MP 136     // msg LDS pitch

using bf16x8 = __bf16 __attribute__((ext_vector_type(8)));
using fx4    = float __attribute__((ext_vector_type(4)));

// Single fused kernel, no workspace: adj streamed+bitpacked in-loop (A),
// node staged fp32 in NATIVE layout via async DMA with granule rotation (B,
// converted to bf16 at LDS->reg time), W converted from fp32 in the epilogue.
__global__ __launch_bounds__(256, 1) void v2h_main(const float* __restrict__ adj,
                                                   const float* __restrict__ node,
                                                   const float* __restrict__ W,
                                                   const float* __restrict__ bias,
                                                   float* __restrict__ out) {
    // Bs granule placement: row n, LDS slot sl holds source granule
    // fs = (sl - 2*((n>>3)&3)) & 31  -> read slot for float f: ((f>>2)+2*((n>>3)&3))&31.
    __shared__ __align__(16) float Bs[2][64][128];           // 64 KB fp32 tiles (dbuf)
    __shared__ __align__(16) unsigned long long Abits[2][64];// 1 KB bit tiles (dbuf)
    __shared__ float normS[BM];                              // 256 B
    __shared__ __align__(16) __bf16 Ms[BM * MP];             // 17.4 KB

    const int t    = threadIdx.x;
    const int bid  = blockIdx.x;
    const int b    = bid & 7;            // batch -> XCD L2 locality
    const int e0   = (bid >> 3) * BM;
    const int w    = t >> 6;             // wave id = f-group (32 cols)
    const int lane = t & 63;
    const int l15  = lane & 15;
    const int quad = lane >> 4;

    // adj stream: row w*16+(lane>>2), col-segment (lane&3)*16
    const int ar   = lane >> 2;
    const int acs  = lane & 3;
    const int arow = w * 16 + ar;
    const float* aRow = adj + ((size_t)b * E_ + e0 + arow) * N_ + acs * 16;
    const float* nB   = node + (size_t)b * N_ * F_;

    auto issue_dma = [&](int k0, int buf) {
#pragma unroll
        for (int p = 0; p < 8; ++p) {
            int idx = t + 256 * p;               // 0..2047 granules (16B each)
            int n   = idx >> 5;                  // 0..63 (k row)
            int sl  = idx & 31;                  // LDS slot within row
            int fs  = (sl - 2 * ((n >> 3) & 3)) & 31;   // source granule (rotation)
            const float* src = nB + (size_t)(k0 + n) * F_ + fs * 4;
            float* dst = &Bs[buf][0][0] + (size_t)(w * 64 + 256 * p) * 4; // wave-uniform
            __builtin_amdgcn_global_load_lds(
                (const __attribute__((address_space(1))) void*)src,
                (__attribute__((address_space(3))) void*)dst, 16, 0, 0);
        }
    };

    auto cvt16 = [](float4 v0, float4 v1, float4 v2, float4 v3) -> unsigned {
        unsigned m = 0;
        m |= (v0.x == -1.f) ? 1u     : 0u;
        m |= (v0.y == -1.f) ? 2u     : 0u;
        m |= (v0.z == -1.f) ? 4u     : 0u;
        m |= (v0.w == -1.f) ? 8u     : 0u;
        m |= (v1.x == -1.f) ? 16u    : 0u;
        m |= (v1.y == -1.f) ? 32u    : 0u;
        m |= (v1.z == -1.f) ? 64u    : 0u;
        m |= (v1.w == -1.f) ? 128u   : 0u;
        m |= (v2.x == -1.f) ? 256u   : 0u;
        m |= (v2.y == -1.f) ? 512u   : 0u;
        m |= (v2.z == -1.f) ? 1024u  : 0u;
        m |= (v2.w == -1.f) ? 2048u  : 0u;
        m |= (v3.x == -1.f) ? 4096u  : 0u;
        m |= (v3.y == -1.f) ? 8192u  : 0u;
        m |= (v3.z == -1.f) ? 16384u : 0u;
        m |= (v3.w == -1.f) ? 32768u : 0u;
        return m;
    };

    auto unpack = [](unsigned byte) -> bf16x8 {
        union { unsigned u[4]; bf16x8 v; } r;
        r.u[0] = ((byte &   1u) ? 0x3F80u : 0u) | ((byte &   2u) ? 0x3F800000u : 0u);
        r.u[1] = ((byte &   4u) ? 0x3F80u : 0u) | ((byte &   8u) ? 0x3F800000u : 0u);
        r.u[2] = ((byte &  16u) ? 0x3F80u : 0u) | ((byte &  32u) ? 0x3F800000u : 0u);
        r.u[3] = ((byte &  64u) ? 0x3F80u : 0u) | ((byte & 128u) ? 0x3F800000u : 0u);
        return r.v;
    };

    // per-lane B read column (constant over the whole K-loop; same for both
    // k-granules since (n>>3)&3 == quad for rows quad*8+j and (4+quad)*8+j)
    int colf[2];
#pragma unroll
    for (int ft = 0; ft < 2; ++ft) {
        int f = w * 32 + ft * 16 + l15;
        colf[ft] = (((f >> 2) + 2 * quad) & 31) * 4 + (f & 3);
    }

    fx4 acc[MT][2] = {};
    int cnt = 0;

    // ---- prologue ----
    float4 a0 = *(const float4*)(aRow + 0);
    float4 a1 = *(const float4*)(aRow + 4);
    float4 a2 = *(const float4*)(aRow + 8);
    float4 a3 = *(const float4*)(aRow + 12);
    issue_dma(0, 0);
    {
        unsigned bits = cvt16(a0, a1, a2, a3);
        ((unsigned short*)&Abits[0][arow])[acs] = (unsigned short)bits;
        cnt += __popc(bits);
    }
    a0 = *(const float4*)(aRow + BK + 0);
    a1 = *(const float4*)(aRow + BK + 4);
    a2 = *(const float4*)(aRow + BK + 8);
    a3 = *(const float4*)(aRow + BK + 12);

#pragma unroll
    for (int m = 0; m < 32; ++m) {
        const int buf = m & 1;
        __syncthreads();   // drains B-DMA(m) + adj regs; Abits[buf] visible

        if (m < 31) {
            issue_dma((m + 1) * BK, buf ^ 1);
            unsigned bits = cvt16(a0, a1, a2, a3);   // tile m+1
            ((unsigned short*)&Abits[buf ^ 1][arow])[acs] = (unsigned short)bits;
            cnt += __popc(bits);
        }
        if (m < 30) {
            const float* ap = aRow + (m + 2) * BK;
            a0 = *(const float4*)(ap + 0);
            a1 = *(const float4*)(ap + 4);
            a2 = *(const float4*)(ap + 8);
            a3 = *(const float4*)(ap + 12);
        }

        // ---- A fragments from Abits[buf] ----
        bf16x8 af0[MT], af1[MT];
#pragma unroll
        for (int mt = 0; mt < MT; ++mt) {
            unsigned long long v = Abits[buf][mt * 16 + l15];
            unsigned lo = (unsigned)v, hi = (unsigned)(v >> 32);
            af0[mt] = unpack((lo >> (8 * quad)) & 255u);
            af1[mt] = unpack((hi >> (8 * quad)) & 255u);
        }

        // ---- B fragments: 8 stride-128 fp32 LDS reads + cvt (2-way banks = free) ----
#pragma unroll
        for (int ft = 0; ft < 2; ++ft) {
            bf16x8 b0, b1;
            {
                const float* bp = &Bs[buf][quad * 8][0] + colf[ft];
#pragma unroll
                for (int jj = 0; jj < 8; ++jj) b0[jj] = (__bf16)bp[jj * 128];
            }
            {
                const float* bp = &Bs[buf][(4 + quad) * 8][0] + colf[ft];
#pragma unroll
                for (int jj = 0; jj < 8; ++jj) b1[jj] = (__bf16)bp[jj * 128];
            }
#pragma unroll
            for (int mt = 0; mt < MT; ++mt)
                acc[mt][ft] = __builtin_amdgcn_mfma_f32_16x16x32_bf16(af0[mt], b0, acc[mt][ft], 0, 0, 0);
#pragma unroll
            for (int mt = 0; mt < MT; ++mt)
                acc[mt][ft] = __builtin_amdgcn_mfma_f32_16x16x32_bf16(af1[mt], b1, acc[mt][ft], 0, 0, 0);
        }
    }

    // ---- norm: reduce count over the 4 col-segment threads of each row ----
    {
        float c = (float)cnt;
        c += __shfl_xor(c, 1);
        c += __shfl_xor(c, 2);
        if (acs == 0)
            normS[arow] = 1.f / fmaxf(c, 1.f);
    }
    __syncthreads();

    // ---- scale by 1/count, write msg bf16 to LDS in [m][f] layout ----
    const int rbase = quad * 4;
    float4 rn[MT];
#pragma unroll
    for (int mt = 0; mt < MT; ++mt)
        rn[mt] = *(const float4*)&normS[mt * 16 + rbase];

#pragma unroll
    for (int ft = 0; ft < 2; ++ft) {
        int fcol = w * 32 + ft * 16 + l15;
#pragma unroll
        for (int mt = 0; mt < MT; ++mt) {
            const float* rr = (const float*)&rn[mt];
#pragma unroll
            for (int r = 0; r < 4; ++r)
                Ms[(mt * 16 + rbase + r) * MP + fcol] = (__bf16)(acc[mt][ft][r] * rr[r]);
        }
    }
    __syncthreads();

    // ---- second GEMM: W read fp32 direct from global (L2-hot), cvt in regs ----
    fx4 acc2[MT][2] = {};
#pragma unroll
    for (int ks = 0; ks < 4; ++ks) {
        bf16x8 afm[MT];
#pragma unroll
        for (int mt = 0; mt < MT; ++mt)
            afm[mt] = *(const bf16x8*)&Ms[(mt * 16 + l15) * MP + ks * 32 + quad * 8];
#pragma unroll
        for (int gt = 0; gt < 2; ++gt) {
            int g = w * 32 + gt * 16 + l15;
            const float* wp = W + (size_t)g * F_ + ks * 32 + quad * 8;
            float4 wa = *(const float4*)wp;
            float4 wb = *(const float4*)(wp + 4);
            bf16x8 wfr;
            wfr[0] = (__bf16)wa.x; wfr[1] = (__bf16)wa.y;
            wfr[2] = (__bf16)wa.z; wfr[3] = (__bf16)wa.w;
            wfr[4] = (__bf16)wb.x; wfr[5] = (__bf16)wb.y;
            wfr[6] = (__bf16)wb.z; wfr[7] = (__bf16)wb.w;
#pragma unroll
            for (int mt = 0; mt < MT; ++mt)
                acc2[mt][gt] = __builtin_amdgcn_mfma_f32_16x16x32_bf16(afm[mt], wfr, acc2[mt][gt], 0, 0, 0);
        }
    }

    // ---- bias + relu + store (all m-tiles) ----
#pragma unroll
    for (int gt = 0; gt < 2; ++gt) {
        int g = w * 32 + gt * 16 + l15;
        float bb = bias[g];
#pragma unroll
        for (int mt = 0; mt < MT; ++mt) {
#pragma unroll
            for (int r = 0; r < 4; ++r) {
                int e = e0 + mt * 16 + rbase + r;
                float v = acc2[mt][gt][r] + bb;
                out[((size_t)b * E_ + e) * F_ + g] = fmaxf(v, 0.f);
            }
        }
    }
}

extern "C" void kernel_launch(void* const* d_in, const int* in_sizes, int n_in,
                              void* d_out, int out_size, void* d_ws, size_t ws_size,
                              hipStream_t stream) {
    const float* node = (const float*)d_in[0];   // [B,N,F]
    const float* adj  = (const float*)d_in[1];   // [B,E,N]
    const float* W    = (const float*)d_in[2];   // [F,F]
    const float* bias = (const float*)d_in[3];   // [F]
    float* out = (float*)d_out;                  // [B,E,F]

    v2h_main<<<256, 256, 0, stream>>>(adj, node, W, bias, out);
}

// Round 12
// 221.617 us; speedup vs baseline: 1.2729x; 1.0450x over previous
//
#include <hip/hip_runtime.h>
#include <hip/hip_bf16.h>

#define B_ 8
#define E_ 2048
#define N_ 2048
#define F_ 128

#define BM 32      // hyperedge rows per block (2 m-tiles of 16)
#define MT 2       // m-tiles
#define BK 64      // K chunk (elements)
#define MP 136     // msg LDS pitch

using bf16x8 = __bf16 __attribute__((ext_vector_type(8)));
using fx4    = float __attribute__((ext_vector_type(4)));

// ---------------- prep: node [B][N][F] f32 -> nodeT [B][F][N] bf16 ----------------
__global__ __launch_bounds__(256) void prep_node(const float* __restrict__ node,
                                                 __bf16* __restrict__ nodeT) {
    const int bid = blockIdx.x;          // 512 blocks
    const int b   = bid & 7;
    const int n0  = (bid >> 3) * 32;
    const int t   = threadIdx.x;
    const int f   = t & 127;
    const int nb  = n0 + (t >> 7) * 16;

    const float* src = node + ((size_t)b * N_ + nb) * F_ + f;
    __bf16 h[16];
#pragma unroll
    for (int i = 0; i < 16; ++i)
        h[i] = (__bf16)src[(size_t)i * F_];

    __bf16* dst = nodeT + ((size_t)b * F_ + f) * N_ + nb;
    *(uint4*)&dst[0] = *(const uint4*)&h[0];
    *(uint4*)&dst[8] = *(const uint4*)&h[8];
}

// ---------------- main: BM=32, grid 512 (2 blocks/CU), fused adj stream ----------
__global__ __launch_bounds__(256, 2) void v2h_main(const float* __restrict__ adj,
                                                   const __bf16* __restrict__ nodeT,
                                                   const float* __restrict__ W,
                                                   const float* __restrict__ bias,
                                                   float* __restrict__ out) {
    __shared__ __align__(16) __bf16 Bs[2][128][64];          // 32 KB, swizzled DMA layout
    __shared__ __align__(16) unsigned long long Abits[2][BM];// 512 B, dbuf bit tiles
    __shared__ float normS[BM];                              // 128 B
    __shared__ __align__(16) __bf16 Ms[BM * MP];             // 8.7 KB

    const int t    = threadIdx.x;
    const int bid  = blockIdx.x;
    const int b    = bid & 7;            // batch -> XCD L2 locality for nodeT[b]
    const int e0   = (bid >> 3) * BM;    // bid>>3 in 0..63
    const int w    = t >> 6;             // wave id = f-group (32 cols)
    const int lane = t & 63;
    const int l15  = lane & 15;
    const int quad = lane >> 4;

    // adj stream: row ar = t>>3 (0..31), col-segment (t&7)*8 (8 floats)
    const int ar  = t >> 3;
    const int acs = t & 7;
    const float* aRow = adj + ((size_t)b * E_ + e0 + ar) * N_ + acs * 8;
    const __bf16* nTB = nodeT + (size_t)b * F_ * N_;

    auto issue_dma = [&](int k0, int buf) {
#pragma unroll
        for (int p = 0; p < 4; ++p) {
            int idx = t + 256 * p;               // 0..1023
            int f   = idx >> 3;                  // 0..127
            int sl  = idx & 7;                   // LDS slot
            int g   = sl ^ (f & 7);              // global granule (XOR swizzle)
            const __bf16* src = nTB + (size_t)f * N_ + k0 + g * 8;
            __bf16* dst = &Bs[buf][0][0] + (size_t)(w * 64 + 256 * p) * 8; // wave-uniform
            __builtin_amdgcn_global_load_lds(
                (const __attribute__((address_space(1))) void*)src,
                (__attribute__((address_space(3))) void*)dst, 16, 0, 0);
        }
    };

    auto cvt8 = [](float4 v0, float4 v1) -> unsigned {
        unsigned m = 0;
        m |= (v0.x == -1.f) ? 1u   : 0u;
        m |= (v0.y == -1.f) ? 2u   : 0u;
        m |= (v0.z == -1.f) ? 4u   : 0u;
        m |= (v0.w == -1.f) ? 8u   : 0u;
        m |= (v1.x == -1.f) ? 16u  : 0u;
        m |= (v1.y == -1.f) ? 32u  : 0u;
        m |= (v1.z == -1.f) ? 64u  : 0u;
        m |= (v1.w == -1.f) ? 128u : 0u;
        return m;
    };

    auto unpack = [](unsigned byte) -> bf16x8 {
        union { unsigned u[4]; bf16x8 v; } r;
        r.u[0] = ((byte &   1u) ? 0x3F80u : 0u) | ((byte &   2u) ? 0x3F800000u : 0u);
        r.u[1] = ((byte &   4u) ? 0x3F80u : 0u) | ((byte &   8u) ? 0x3F800000u : 0u);
        r.u[2] = ((byte &  16u) ? 0x3F80u : 0u) | ((byte &  32u) ? 0x3F800000u : 0u);
        r.u[3] = ((byte &  64u) ? 0x3F80u : 0u) | ((byte & 128u) ? 0x3F800000u : 0u);
        return r.v;
    };

    fx4 acc[MT][2] = {};
    int cnt = 0;

    // ---- prologue: adj tile 0 -> bits -> Abits[0]; DMA(0); tile 1 in regs ----
    float4 a0 = *(const float4*)(aRow + 0);
    float4 a1 = *(const float4*)(aRow + 4);
    issue_dma(0, 0);
    {
        unsigned bits = cvt8(a0, a1);
        ((unsigned char*)&Abits[0][ar])[acs] = (unsigned char)bits;
        cnt += __popc(bits);
    }
    a0 = *(const float4*)(aRow + BK + 0);
    a1 = *(const float4*)(aRow + BK + 4);

#pragma unroll
    for (int m = 0; m < 32; ++m) {
        const int buf = m & 1;
        __syncthreads();   // drains B-DMA(m) + adj regs; Abits[buf] visible

        if (m < 31) {
            issue_dma((m + 1) * BK, buf ^ 1);
            unsigned bits = cvt8(a0, a1);            // tile m+1
            ((unsigned char*)&Abits[buf ^ 1][ar])[acs] = (unsigned char)bits;
            cnt += __popc(bits);
        }
        if (m < 30) {
            const float* ap = aRow + (m + 2) * BK;   // prefetch distance 2
            a0 = *(const float4*)(ap + 0);
            a1 = *(const float4*)(ap + 4);
        }

        // ---- A fragments from Abits[buf]: byte (kgran) of row-u64 ----
        bf16x8 af0[MT], af1[MT];
#pragma unroll
        for (int mt = 0; mt < MT; ++mt) {
            unsigned long long v = Abits[buf][mt * 16 + l15];
            unsigned lo = (unsigned)v, hi = (unsigned)(v >> 32);
            af0[mt] = unpack((lo >> (8 * quad)) & 255u);
            af1[mt] = unpack((hi >> (8 * quad)) & 255u);
        }

        // ---- B frag = row f, k-granule qg, at swizzled slot qg^(f&7) ----
#pragma unroll
        for (int ft = 0; ft < 2; ++ft) {
            int f  = w * 32 + ft * 16 + l15;
            int q0 = quad ^ (f & 7);
            int q1 = (4 + quad) ^ (f & 7);
            bf16x8 b0 = *(const bf16x8*)&Bs[buf][f][q0 * 8];
#pragma unroll
            for (int mt = 0; mt < MT; ++mt)
                acc[mt][ft] = __builtin_amdgcn_mfma_f32_16x16x32_bf16(af0[mt], b0, acc[mt][ft], 0, 0, 0);
            bf16x8 b1 = *(const bf16x8*)&Bs[buf][f][q1 * 8];
#pragma unroll
            for (int mt = 0; mt < MT; ++mt)
                acc[mt][ft] = __builtin_amdgcn_mfma_f32_16x16x32_bf16(af1[mt], b1, acc[mt][ft], 0, 0, 0);
        }
    }

    // ---- norm: reduce count over the 8 col-segment threads of each row ----
    {
        float c = (float)cnt;
        c += __shfl_xor(c, 1);
        c += __shfl_xor(c, 2);
        c += __shfl_xor(c, 4);
        if (acs == 0)
            normS[ar] = 1.f / fmaxf(c, 1.f);
    }
    __syncthreads();

    // ---- scale by 1/count, write msg bf16 to LDS in [m][f] layout ----
    const int rbase = quad * 4;
    float4 rn[MT];
#pragma unroll
    for (int mt = 0; mt < MT; ++mt)
        rn[mt] = *(const float4*)&normS[mt * 16 + rbase];

#pragma unroll
    for (int ft = 0; ft < 2; ++ft) {
        int fcol = w * 32 + ft * 16 + l15;
#pragma unroll
        for (int mt = 0; mt < MT; ++mt) {
            const float* rr = (const float*)&rn[mt];
#pragma unroll
            for (int r = 0; r < 4; ++r)
                Ms[(mt * 16 + rbase + r) * MP + fcol] = (__bf16)(acc[mt][ft][r] * rr[r]);
        }
    }
    __syncthreads();

    // ---- second GEMM: W read fp32 direct from global (L2-hot), cvt in regs ----
    fx4 acc2[MT][2] = {};
#pragma unroll
    for (int ks = 0; ks < 4; ++ks) {
        bf16x8 afm[MT];
#pragma unroll
        for (int mt = 0; mt < MT; ++mt)
            afm[mt] = *(const bf16x8*)&Ms[(mt * 16 + l15) * MP + ks * 32 + quad * 8];
#pragma unroll
        for (int gt = 0; gt < 2; ++gt) {
            int g = w * 32 + gt * 16 + l15;
            const float* wp = W + (size_t)g * F_ + ks * 32 + quad * 8;
            float4 wa = *(const float4*)wp;
            float4 wb = *(const float4*)(wp + 4);
            bf16x8 wfr;
            wfr[0] = (__bf16)wa.x; wfr[1] = (__bf16)wa.y;
            wfr[2] = (__bf16)wa.z; wfr[3] = (__bf16)wa.w;
            wfr[4] = (__bf16)wb.x; wfr[5] = (__bf16)wb.y;
            wfr[6] = (__bf16)wb.z; wfr[7] = (__bf16)wb.w;
#pragma unroll
            for (int mt = 0; mt < MT; ++mt)
                acc2[mt][gt] = __builtin_amdgcn_mfma_f32_16x16x32_bf16(afm[mt], wfr, acc2[mt][gt], 0, 0, 0);
        }
    }

    // ---- bias + relu + store (both m-tiles) ----
#pragma unroll
    for (int gt = 0; gt < 2; ++gt) {
        int g = w * 32 + gt * 16 + l15;
        float bb = bias[g];
#pragma unroll
        for (int mt = 0; mt < MT; ++mt) {
#pragma unroll
            for (int r = 0; r < 4; ++r) {
                int e = e0 + mt * 16 + rbase + r;
                float v = acc2[mt][gt][r] + bb;
                out[((size_t)b * E_ + e) * F_ + g] = fmaxf(v, 0.f);
            }
        }
    }
}

extern "C" void kernel_launch(void* const* d_in, const int* in_sizes, int n_in,
                              void* d_out, int out_size, void* d_ws, size_t ws_size,
                              hipStream_t stream) {
    const float* node = (const float*)d_in[0];   // [B,N,F]
    const float* adj  = (const float*)d_in[1];   // [B,E,N]
    const float* W    = (const float*)d_in[2];   // [F,F]
    const float* bias = (const float*)d_in[3];   // [F]
    float* out = (float*)d_out;                  // [B,E,F]

    __bf16* nodeT = (__bf16*)d_ws;               // 8 MB

    prep_node<<<512, 256, 0, stream>>>(node, nodeT);
    v2h_main<<<512, 256, 0, stream>>>(adj, nodeT, W, bias, out);
}